// Round 4
// baseline (383.425 us; speedup 1.0000x reference)
//
#include <hip/hip_runtime.h>
#include <stdint.h>

// DropBlock: x:(64,64,112,112) f32. mask over (B,H,W) from JAX threefry
// bernoulli(seed 42) [partitionable layout, verified R1], eroded by 6x6 min
// window (pad (2,3)), out = x*mask * (B*H*W)/sum(x*mask).
//
// R4 = R1 structure, k_sum restructured for contiguous streaming.
//  k_mask : dim3(28,64) x 256. 4 mask rows/block from a 9-row threefry halo.
//  k_sum  : dim3(16,64) x 256. Block (cg,b). OUTER loop over channel c,
//           INNER contiguous hw4 sweep -> each block streams one contiguous
//           50 KB window at a time (copy-ubench-like), instead of 4
//           interleaved streams 200 KB apart per thread (theory: that
//           interleave was the 2.5 TB/s wall; floor is ~33 us).
//           Mask word re-read per channel: L1/L2-hit, negligible.
//           No atomics, NO fences (R2: +46 us, never again).
//  k_scale: dim3(64,64) x 256 (~45 us, near floor). Prologue redundantly
//           reduces 1024 partials (L2 broadcast, identical in every block,
//           ordering by stream semantics alone). NT stores for out.
#define B_      64
#define C_      64
#define H_      112
#define W_      112
#define HW_     12544      // H*W
#define HW4_    3136       // H*W/4
#define CHW4_   200704     // C*H*W/4
#define NPART   1024       // 16 c-groups * 64 b

typedef float v4f __attribute__((ext_vector_type(4)));  // NT-store-compatible

__device__ __forceinline__ uint32_t rotl32(uint32_t x, int d) {
  return (x << d) | (x >> (32 - d));
}

// Threefry-2x32, key=(0,42), counter=(0,i), out = x0^x1 (partitionable JAX).
__device__ __forceinline__ uint32_t threefry_bits(uint32_t i) {
  const uint32_t k0 = 0u, k1 = 42u;
  const uint32_t k2 = k0 ^ k1 ^ 0x1BD11BDAu;
  uint32_t x0 = 0u, x1 = i;
  x0 += k0; x1 += k1;
#define TF_R(r) { x0 += x1; x1 = rotl32(x1, (r)); x1 ^= x0; }
  TF_R(13) TF_R(15) TF_R(26) TF_R(6)
  x0 += k1; x1 += k2 + 1u;
  TF_R(17) TF_R(29) TF_R(16) TF_R(24)
  x0 += k2; x1 += k0 + 2u;
  TF_R(13) TF_R(15) TF_R(26) TF_R(6)
  x0 += k0; x1 += k1 + 3u;
  TF_R(17) TF_R(29) TF_R(16) TF_R(24)
  x0 += k1; x1 += k2 + 4u;
  TF_R(13) TF_R(15) TF_R(26) TF_R(6)
  x0 += k2; x1 += k0 + 5u;
#undef TF_R
  return x0 ^ x1;
}

// Block (rchunk, b): output mask rows r0..r0+3 of image b.
// t0 = 9 halo rows of bernoulli init (rows outside image = 1, identity for
// min-erosion -> matches the reference's clamped window bounds exactly).
__global__ __launch_bounds__(256) void k_mask(uint8_t* __restrict__ mask,
                                              float p) {
  __shared__ uint8_t t0[9 * W_];   // init rows r0-2 .. r0+6
  __shared__ uint8_t t1[4 * W_];   // H-eroded rows r0 .. r0+3
  const int b = blockIdx.y;
  const int r0 = blockIdx.x << 2;
  const int tid = threadIdx.x;
  for (int i = tid; i < 9 * W_; i += 256) {
    int row = i / W_;
    int j = i - row * W_;
    int r = r0 - 2 + row;
    uint8_t v = 1;
    if (r >= 0 && r < H_) {
      uint32_t bits = threefry_bits((uint32_t)(b * HW_ + r * W_ + j));
      float u = __uint_as_float((bits >> 9) | 0x3f800000u) - 1.0f;  // [0,1)
      v = (u < p) ? (uint8_t)1 : (uint8_t)0;
    }
    t0[i] = v;
  }
  __syncthreads();
  for (int i = tid; i < 4 * W_; i += 256) {   // erode along H (window 6)
    int row = i / W_;                          // t0 rows row..row+5 (in [0,8])
    int j = i - row * W_;
    unsigned v = t0[row * W_ + j];
    v &= t0[(row + 1) * W_ + j];
    v &= t0[(row + 2) * W_ + j];
    v &= t0[(row + 3) * W_ + j];
    v &= t0[(row + 4) * W_ + j];
    v &= t0[(row + 5) * W_ + j];
    t1[i] = (uint8_t)v;
  }
  __syncthreads();
  for (int i = tid; i < 4 * W_; i += 256) {   // erode along W (window 6)
    int row = i / W_;
    int j = i - row * W_;
    int lo = j - 2; if (lo < 0) lo = 0;
    int hi = j + 3; if (hi > W_ - 1) hi = W_ - 1;
    unsigned v = 1u;
    for (int jj = lo; jj <= hi; ++jj) v &= t1[row * W_ + jj];
    mask[b * HW_ + (r0 + row) * W_ + j] = (uint8_t)v;
  }
}

// Block (cg, b): sum x*mask over channels 4cg..4cg+3 of image b.
// Outer c-loop, inner contiguous hw4 sweep: one contiguous stream at a time.
__global__ __launch_bounds__(256) void k_sum(const float4* __restrict__ x4,
                                             const uint8_t* __restrict__ mask,
                                             float* __restrict__ partials) {
  const int b = blockIdx.y;
  const int cg = blockIdx.x;                   // 0..15, 4 channels each
  const float4* xp = x4 + (size_t)b * CHW4_ + (size_t)(cg * 4) * HW4_;
  const uint32_t* m32 = (const uint32_t*)(mask + b * HW_);
  float acc = 0.0f;
  for (int c = 0; c < 4; ++c) {
    const float4* xc = xp + (size_t)c * HW4_;
#pragma unroll 4
    for (int hw4 = threadIdx.x; hw4 < HW4_; hw4 += 256) {
      uint32_t mw = m32[hw4];                  // L1/L2-hit after c=0
      float4 v = xc[hw4];
      acc += (mw & 0x000000ffu) ? v.x : 0.0f;
      acc += (mw & 0x0000ff00u) ? v.y : 0.0f;
      acc += (mw & 0x00ff0000u) ? v.z : 0.0f;
      acc += (mw & 0xff000000u) ? v.w : 0.0f;
    }
  }
  for (int off = 32; off > 0; off >>= 1)
    acc += __shfl_down(acc, off, 64);
  __shared__ float part[4];
  if ((threadIdx.x & 63) == 0) part[threadIdx.x >> 6] = acc;
  __syncthreads();
  if (threadIdx.x == 0)
    partials[b * 16 + cg] = part[0] + part[1] + part[2] + part[3];
}

// Block (c, b): prologue reduces all 1024 partials (identical result in every
// block -> no extra launch, no fence; stream order guarantees visibility),
// then scales 1 channel of 1 image.
__global__ __launch_bounds__(256) void k_scale(const float4* __restrict__ x4,
                                               const uint8_t* __restrict__ mask,
                                               const float* __restrict__ partials,
                                               v4f* __restrict__ out4) {
  __shared__ float sscale;
  {
    double a = 0.0;
    for (int i = threadIdx.x; i < NPART; i += 256)
      a += (double)partials[i];
    for (int off = 32; off > 0; off >>= 1)
      a += __shfl_down(a, off, 64);
    __shared__ double dp[4];
    if ((threadIdx.x & 63) == 0) dp[threadIdx.x >> 6] = a;
    __syncthreads();
    if (threadIdx.x == 0) {
      double s = dp[0] + dp[1] + dp[2] + dp[3];
      sscale = (float)(802816.0 / s);           // B*H*W / sum
    }
    __syncthreads();
  }
  const float scale = sscale;
  const int b = blockIdx.y;
  const size_t base = (size_t)b * CHW4_ + (size_t)blockIdx.x * HW4_;
  const float4* xp = x4 + base;
  v4f* op = out4 + base;
  const uint32_t* m32 = (const uint32_t*)(mask + b * HW_);
  for (int hw4 = threadIdx.x; hw4 < HW4_; hw4 += 256) {
    uint32_t mw = m32[hw4];
    float4 v = xp[hw4];
    v4f o;
    o.x = (mw & 0x000000ffu) ? v.x * scale : 0.0f;
    o.y = (mw & 0x0000ff00u) ? v.y * scale : 0.0f;
    o.z = (mw & 0x00ff0000u) ? v.z * scale : 0.0f;
    o.w = (mw & 0xff000000u) ? v.w * scale : 0.0f;
    __builtin_nontemporal_store(o, &op[hw4]);
  }
}

extern "C" void kernel_launch(void* const* d_in, const int* in_sizes, int n_in,
                              void* d_out, int out_size, void* d_ws, size_t ws_size,
                              hipStream_t stream) {
  const float* x = (const float*)d_in[0];
  float* out = (float*)d_out;
  char* ws = (char*)d_ws;
  float* partials = (float*)(ws + 16);         // 4KB  @ 16
  uint8_t* mask = (uint8_t*)(ws + 16384);      // 0.8MB@ 16K
  // (partials fully overwritten by k_sum each call; poison-safe, no memset)

  // gamma exactly as Python: (1.0-0.9) * H^2 / (bs^2 * (H-bs+1)^2)
  double gamma = (1.0 - 0.9) * 12544.0 / 550564.0;
  float p = (float)(1.0 - gamma);              // f32 compare like JAX `u < p`

  k_mask <<<dim3(28, 64), 256, 0, stream>>>(mask, p);
  k_sum  <<<dim3(16, 64), 256, 0, stream>>>((const float4*)x, mask, partials);
  k_scale<<<dim3(64, 64), 256, 0, stream>>>((const float4*)x, mask, partials,
                                            (v4f*)out);
}

// Round 6
// 374.090 us; speedup vs baseline: 1.0250x; 1.0250x over previous
//
#include <hip/hip_runtime.h>
#include <stdint.h>

// DropBlock: x:(64,64,112,112) f32. mask over (B,H,W) from JAX threefry
// bernoulli(seed 42) [partitionable layout, verified R1], eroded by 6x6 min
// window (pad (2,3)), out = x*mask * (B*H*W)/sum(x*mask).
//
// R6: 2 kernels (mask+sum fused at block level; NO cross-block deps inside a
// kernel -- R5's cooperative grid.sync was not coherent cross-XCD here, and
// R2's per-block fences cost +46 us; kernel boundary is the only proven
// coherence point).
//  k_masksum: dim3(28,64) x 256. Block (rc,b): builds mask rows r0..r0+3 of
//             image b in LDS (9-row threefry halo, separable 6x6 erosion --
//             byte-identical to R4's k_mask), writes them to global mask for
//             k_scale, then computes the masked sum over ALL 64 channels of
//             those 4 rows: per channel the 4-row slab x[b,c,r0:r0+4,:] is
//             1792 B contiguous. Mask bits come from LDS (no global re-read).
//             One partial per block -> partials[1792].
//  k_scale  : dim3(64,64) x 256 (unchanged, proven). Prologue redundantly
//             reduces 1792 partials (L2 broadcast, identical in every block,
//             fixed order -> deterministic), then scales 1 channel of 1
//             image; NT stores keep x L3-resident.
#define B_      64
#define C_      64
#define H_      112
#define W_      112
#define HW_     12544      // H*W
#define HW4_    3136       // H*W/4 (float4 per channel plane)
#define CHW4_   200704     // C*H*W/4
#define NPART   1792       // 28 row-chunks * 64 b
#define SLABF4  7168       // 64 ch * 112 f4 (4 rows * 28 f4) per block

typedef float v4f __attribute__((ext_vector_type(4)));  // NT-store-compatible

__device__ __forceinline__ uint32_t rotl32(uint32_t x, int d) {
  return (x << d) | (x >> (32 - d));
}

// Threefry-2x32, key=(0,42), counter=(0,i), out = x0^x1 (partitionable JAX).
__device__ __forceinline__ uint32_t threefry_bits(uint32_t i) {
  const uint32_t k0 = 0u, k1 = 42u;
  const uint32_t k2 = k0 ^ k1 ^ 0x1BD11BDAu;
  uint32_t x0 = 0u, x1 = i;
  x0 += k0; x1 += k1;
#define TF_R(r) { x0 += x1; x1 = rotl32(x1, (r)); x1 ^= x0; }
  TF_R(13) TF_R(15) TF_R(26) TF_R(6)
  x0 += k1; x1 += k2 + 1u;
  TF_R(17) TF_R(29) TF_R(16) TF_R(24)
  x0 += k2; x1 += k0 + 2u;
  TF_R(13) TF_R(15) TF_R(26) TF_R(6)
  x0 += k0; x1 += k1 + 3u;
  TF_R(17) TF_R(29) TF_R(16) TF_R(24)
  x0 += k1; x1 += k2 + 4u;
  TF_R(13) TF_R(15) TF_R(26) TF_R(6)
  x0 += k2; x1 += k0 + 5u;
#undef TF_R
  return x0 ^ x1;
}

// Block (rc, b): mask rows r0..r0+3 of image b + masked sum of all channels
// over those rows.
__global__ __launch_bounds__(256) void k_masksum(
    const float4* __restrict__ x4, uint8_t* __restrict__ mask,
    float* __restrict__ partials, float p) {
  __shared__ uint8_t t0[9 * W_];    // init rows r0-2 .. r0+6 (OOB rows = 1)
  __shared__ uint8_t t1[4 * W_];    // H-eroded rows r0 .. r0+3
  __shared__ uint32_t m2w[4 * 28];  // final mask, 4B-packed (matches f4 cols)
  const int b = blockIdx.y;
  const int rc = blockIdx.x;
  const int r0 = rc << 2;
  const int tid = threadIdx.x;

  // ---- bernoulli init (9 halo rows) ----
  for (int i = tid; i < 9 * W_; i += 256) {
    int row = i / W_;
    int j = i - row * W_;
    int r = r0 - 2 + row;
    uint8_t v = 1;
    if (r >= 0 && r < H_) {
      uint32_t bits = threefry_bits((uint32_t)(b * HW_ + r * W_ + j));
      float u = __uint_as_float((bits >> 9) | 0x3f800000u) - 1.0f;  // [0,1)
      v = (u < p) ? (uint8_t)1 : (uint8_t)0;
    }
    t0[i] = v;
  }
  __syncthreads();
  // ---- erode along H (window 6: rows row..row+5 of t0) ----
  for (int i = tid; i < 4 * W_; i += 256) {
    int row = i / W_;
    int j = i - row * W_;
    unsigned v = t0[row * W_ + j];
    v &= t0[(row + 1) * W_ + j];
    v &= t0[(row + 2) * W_ + j];
    v &= t0[(row + 3) * W_ + j];
    v &= t0[(row + 4) * W_ + j];
    v &= t0[(row + 5) * W_ + j];
    t1[i] = (uint8_t)v;
  }
  __syncthreads();
  // ---- erode along W (window [j-2, j+3] clamped), write LDS + global ----
  for (int i = tid; i < 4 * W_; i += 256) {
    int row = i / W_;
    int j = i - row * W_;
    int lo = j - 2; if (lo < 0) lo = 0;
    int hi = j + 3; if (hi > W_ - 1) hi = W_ - 1;
    unsigned v = 1u;
    for (int jj = lo; jj <= hi; ++jj) v &= t1[row * W_ + jj];
    ((uint8_t*)m2w)[i] = (uint8_t)v;
    mask[b * HW_ + (r0 + row) * W_ + j] = (uint8_t)v;
  }
  __syncthreads();

  // ---- masked sum over all 64 channels of rows r0..r0+3 ----
  // Flat f4 index f = c*112 + s; s in [0,112): the channel's 4-row slab is
  // contiguous (1792 B). Mask word from LDS: m2w[s].
  const float4* xb = x4 + (size_t)b * CHW4_ + rc * 112;  // + c*3136 below
  float acc = 0.0f;
#pragma unroll 4
  for (int f = tid; f < SLABF4; f += 256) {
    unsigned c = (unsigned)f / 112u;
    unsigned s = (unsigned)f - c * 112u;
    float4 v = xb[c * 3136u + s];
    uint32_t mw = m2w[s];
    acc += (mw & 0x000000ffu) ? v.x : 0.0f;
    acc += (mw & 0x0000ff00u) ? v.y : 0.0f;
    acc += (mw & 0x00ff0000u) ? v.z : 0.0f;
    acc += (mw & 0xff000000u) ? v.w : 0.0f;
  }
  for (int off = 32; off > 0; off >>= 1)
    acc += __shfl_down(acc, off, 64);
  __shared__ float part[4];
  if ((tid & 63) == 0) part[tid >> 6] = acc;
  __syncthreads();
  if (tid == 0)
    partials[b * 28 + rc] = part[0] + part[1] + part[2] + part[3];
}

// Block (c, b): prologue reduces all 1792 partials (identical result in every
// block -> no extra launch, no fence; kernel boundary gives coherence),
// then scales 1 channel of 1 image.
__global__ __launch_bounds__(256) void k_scale(const float4* __restrict__ x4,
                                               const uint8_t* __restrict__ mask,
                                               const float* __restrict__ partials,
                                               v4f* __restrict__ out4) {
  __shared__ float sscale;
  {
    double a = 0.0;
    for (int i = threadIdx.x; i < NPART; i += 256)
      a += (double)partials[i];                // fixed order -> deterministic
    for (int off = 32; off > 0; off >>= 1)
      a += __shfl_down(a, off, 64);
    __shared__ double dp[4];
    if ((threadIdx.x & 63) == 0) dp[threadIdx.x >> 6] = a;
    __syncthreads();
    if (threadIdx.x == 0) {
      double s = dp[0] + dp[1] + dp[2] + dp[3];
      sscale = (float)(802816.0 / s);           // B*H*W / sum
    }
    __syncthreads();
  }
  const float scale = sscale;
  const int b = blockIdx.y;
  const size_t base = (size_t)b * CHW4_ + (size_t)blockIdx.x * HW4_;
  const float4* xp = x4 + base;
  v4f* op = out4 + base;
  const uint32_t* m32 = (const uint32_t*)(mask + b * HW_);
  for (int hw4 = threadIdx.x; hw4 < HW4_; hw4 += 256) {
    uint32_t mw = m32[hw4];
    float4 v = xp[hw4];
    v4f o;
    o.x = (mw & 0x000000ffu) ? v.x * scale : 0.0f;
    o.y = (mw & 0x0000ff00u) ? v.y * scale : 0.0f;
    o.z = (mw & 0x00ff0000u) ? v.z * scale : 0.0f;
    o.w = (mw & 0xff000000u) ? v.w * scale : 0.0f;
    __builtin_nontemporal_store(o, &op[hw4]);
  }
}

extern "C" void kernel_launch(void* const* d_in, const int* in_sizes, int n_in,
                              void* d_out, int out_size, void* d_ws, size_t ws_size,
                              hipStream_t stream) {
  const float* x = (const float*)d_in[0];
  float* out = (float*)d_out;
  char* ws = (char*)d_ws;
  float* partials = (float*)(ws + 16);         // 7KB  @ 16
  uint8_t* mask = (uint8_t*)(ws + 16384);      // 0.8MB@ 16K
  // (partials fully overwritten by k_masksum each call; poison-safe)

  // gamma exactly as Python: (1.0-0.9) * H^2 / (bs^2 * (H-bs+1)^2)
  double gamma = (1.0 - 0.9) * 12544.0 / 550564.0;
  float p = (float)(1.0 - gamma);              // f32 compare like JAX `u < p`

  k_masksum<<<dim3(28, 64), 256, 0, stream>>>((const float4*)x, mask,
                                              partials, p);
  k_scale  <<<dim3(64, 64), 256, 0, stream>>>((const float4*)x, mask,
                                              partials, (v4f*)out);
}